// Round 1
// baseline (1318.371 us; speedup 1.0000x reference)
//
#include <hip/hip_runtime.h>
#include <math.h>

// DCGRU cell, N=8192, B=1, D_IN=2, UNITS=64, K=2, F=66, M=3.
// Internal column layout for x-matrices: [0..63]=state, [64..65]=input, [66..71]=pad.
// adj_mx @ v  ==  adj^T @ (dinv*v) + (dinv*v)   (adj2 = adj + I folded into epilogue)

constexpr int NN      = 8192;
constexpr int UNITS   = 64;
constexpr int CSTRIDE = 72;                 // padded feature stride (floats), 288B rows
constexpr int NS      = NN * CSTRIDE;       // floats per x-matrix
constexpr int BN      = 64;                 // i-tile (output rows) per block
constexpr int BK      = 32;                 // k-tile
constexpr int SPLITS  = 4;                  // split-K partial buffers (deterministic, no atomics)
constexpr int KCHUNK  = NN / SPLITS;        // 2048
constexpr int GN      = 16;                 // nodes per block in gate/final kernels

typedef float v2f __attribute__((ext_vector_type(2)));
static __device__ __forceinline__ v2f s2(float x) { v2f r; r.x = x; r.y = x; return r; }

// ---------------------------------------------------------------- d_inv ----
__global__ __launch_bounds__(256) void k_dinv(const float* __restrict__ adj,
                                              float* __restrict__ dinv) {
  __shared__ float red[4];
  const int row = blockIdx.x;
  const float* rp = adj + (size_t)row * NN;
  float s = 0.f;
  for (int p = threadIdx.x * 4; p < NN; p += 1024) {
    float4 v = *reinterpret_cast<const float4*>(&rp[p]);
    s += (v.x + v.y) + (v.z + v.w);
  }
  for (int off = 32; off > 0; off >>= 1) s += __shfl_down(s, off);
  if ((threadIdx.x & 63) == 0) red[threadIdx.x >> 6] = s;
  __syncthreads();
  if (threadIdx.x == 0) {
    float t = red[0] + red[1] + red[2] + red[3];
    dinv[row] = 1.0f / (t + 1.0f);         // +1 for the added identity diagonal
  }
}

// ------------------------------------------------------------- build x0 ----
__global__ __launch_bounds__(256) void k_build(const float* __restrict__ hx,
                                               const float* __restrict__ inp,
                                               const float* __restrict__ dinv,
                                               float* __restrict__ X0,
                                               float* __restrict__ XS0) {
  int idx = blockIdx.x * 256 + threadIdx.x;      // grid covers exactly NN*CSTRIDE
  int n = idx / CSTRIDE, c = idx % CSTRIDE;
  float v = 0.f;
  if (c < 64)      v = hx[n * UNITS + c];
  else if (c < 66) v = inp[n * 2 + (c - 64)];
  X0[idx]  = v;
  XS0[idx] = dinv[n] * v;
}

// ------------------------------------------------ main GEMM: P = adj^T@U ----
// P[split][i][c] = sum_{k in chunk} adj[k][i] * U[k][c]
__global__ __launch_bounds__(256, 2) void k_gemm(const float* __restrict__ adj,
                                                 const float* __restrict__ U,
                                                 float* __restrict__ P) {
  __shared__ float at[BK][BN];        // 8 KB
  __shared__ float ut[BK][CSTRIDE];   // 9 KB
  const int tid = threadIdx.x;
  const int i0  = blockIdx.x * BN;
  const int k0  = blockIdx.y * KCHUNK;
  const int cg  = tid >> 4;           // 0..15 -> cols cg*4..cg*4+3
  const int ig  = tid & 15;           // 0..15 -> rows ig*4..ig*4+3

  v2f acc[4][2] = {};
  v2f acce[4]   = {};                 // cols 64..65, only cg==0 threads

  for (int kt = 0; kt < KCHUNK; kt += BK) {
    // stage adj tile [BK][BN]: 512 float4, 2 per thread
    {
      int p = tid;
#pragma unroll
      for (int rep = 0; rep < 2; ++rep) {
        int rr = p >> 4, c4 = (p & 15) << 2;
        *reinterpret_cast<float4*>(&at[rr][c4]) =
            *reinterpret_cast<const float4*>(&adj[(size_t)(k0 + kt + rr) * NN + i0 + c4]);
        p += 256;
      }
      // stage U tile [BK][CSTRIDE]: 576 float4
      for (int q = tid; q < BK * (CSTRIDE / 4); q += 256) {
        int rr = q / (CSTRIDE / 4), c4 = (q % (CSTRIDE / 4)) << 2;
        *reinterpret_cast<float4*>(&ut[rr][c4]) =
            *reinterpret_cast<const float4*>(&U[(size_t)(k0 + kt + rr) * CSTRIDE + c4]);
      }
    }
    __syncthreads();
#pragma unroll 8
    for (int kk = 0; kk < BK; ++kk) {
      float4 a4 = *reinterpret_cast<const float4*>(&at[kk][ig << 2]);
      float4 u4 = *reinterpret_cast<const float4*>(&ut[kk][cg << 2]);
      v2f u01; u01.x = u4.x; u01.y = u4.y;
      v2f u23; u23.x = u4.z; u23.y = u4.w;
      float av[4] = {a4.x, a4.y, a4.z, a4.w};
#pragma unroll
      for (int r = 0; r < 4; ++r) {
        acc[r][0] += s2(av[r]) * u01;
        acc[r][1] += s2(av[r]) * u23;
      }
      if (cg == 0) {
        v2f e = *reinterpret_cast<const v2f*>(&ut[kk][64]);
#pragma unroll
        for (int r = 0; r < 4; ++r) acce[r] += s2(av[r]) * e;
      }
    }
    __syncthreads();
  }

  float* Pp = P + (size_t)blockIdx.y * NS + (size_t)i0 * CSTRIDE;
#pragma unroll
  for (int r = 0; r < 4; ++r) {
    int row = ig * 4 + r;
    float4 o = make_float4(acc[r][0].x, acc[r][0].y, acc[r][1].x, acc[r][1].y);
    *reinterpret_cast<float4*>(&Pp[(size_t)row * CSTRIDE + (cg << 2)]) = o;
    if (cg == 0)
      *reinterpret_cast<v2f*>(&Pp[(size_t)row * CSTRIDE + 64]) = acce[r];
  }
}

// ------------------------------------------------------------- epilogues ----
// X = sum(P) + U ; XS = dinv * X          (hop-1 of each gconv)
__global__ __launch_bounds__(256) void k_epiA(const float* __restrict__ P,
                                              const float* __restrict__ U,
                                              const float* __restrict__ dinv,
                                              float* __restrict__ X,
                                              float* __restrict__ XS) {
  int idx = blockIdx.x * 256 + threadIdx.x;      // over NN*66
  int n = idx / 66, c = idx % 66;
  size_t o = (size_t)n * CSTRIDE + c;
  float t = P[o] + P[(size_t)NS + o] + P[2 * (size_t)NS + o] + P[3 * (size_t)NS + o] + U[o];
  X[o]  = t;
  XS[o] = dinv[n] * t;
}

// X2 = 2*(sum(P) + U) - X0                (hop-2, Chebyshev)
__global__ __launch_bounds__(256) void k_epiB(const float* __restrict__ P,
                                              const float* __restrict__ U,
                                              const float* __restrict__ X0,
                                              float* __restrict__ X2) {
  int idx = blockIdx.x * 256 + threadIdx.x;
  int n = idx / 66, c = idx % 66;
  size_t o = (size_t)n * CSTRIDE + c;
  float t = P[o] + P[(size_t)NS + o] + P[2 * (size_t)NS + o] + P[3 * (size_t)NS + o] + U[o];
  X2[o] = 2.f * t - X0[o];
}

// ----------------------------------------------------------- gate matmul ----
// out[n][o] = sigmoid( sum_{c,m} Xm[n][c] * w_ru[f(c)*3+m][o] + b_ru[o] )
// r = out[:64] -> X0/XS0 state cols become r*h (input cols untouched); u -> UG
__global__ __launch_bounds__(256) void k_gates(const float* __restrict__ X0,
                                               const float* __restrict__ X1,
                                               const float* __restrict__ X2,
                                               const float* __restrict__ w_ru,
                                               const float* __restrict__ b_ru,
                                               const float* __restrict__ hx,
                                               const float* __restrict__ dinv,
                                               float* __restrict__ X0out,
                                               float* __restrict__ XS0out,
                                               float* __restrict__ UG) {
  __shared__ float xr[3][GN][66];
  const int n0 = blockIdx.x * GN;
  const int tid = threadIdx.x;
  for (int p = tid; p < GN * 66; p += 256) {
    int nl = p / 66, c = p % 66;
    size_t o = (size_t)(n0 + nl) * CSTRIDE + c;
    xr[0][nl][c] = X0[o];
    xr[1][nl][c] = X1[o];
    xr[2][nl][c] = X2[o];
  }
  __syncthreads();
  const int nl = tid >> 4;
  const int ot = tid & 15;
  const int o0 = ot * 8;
  float acc[8];
#pragma unroll
  for (int j = 0; j < 8; ++j) acc[j] = b_ru[o0 + j];
  for (int c = 0; c < 66; ++c) {
    int f = (c < 64) ? (c + 2) : (c - 64);   // reference feature order: [inp(2), state(64)]
#pragma unroll
    for (int m = 0; m < 3; ++m) {
      float xv = xr[m][nl][c];
      const float* wrow = &w_ru[(size_t)(f * 3 + m) * 128 + o0];
      float4 w0 = *reinterpret_cast<const float4*>(wrow);
      float4 w1 = *reinterpret_cast<const float4*>(wrow + 4);
      acc[0] += xv * w0.x; acc[1] += xv * w0.y; acc[2] += xv * w0.z; acc[3] += xv * w0.w;
      acc[4] += xv * w1.x; acc[5] += xv * w1.y; acc[6] += xv * w1.z; acc[7] += xv * w1.w;
    }
  }
  const int n = n0 + nl;
  const float dv = dinv[n];
  if (o0 < 64) {
#pragma unroll
    for (int j = 0; j < 8; ++j) {
      int o = o0 + j;
      float g = 1.f / (1.f + expf(-acc[j]));
      float v = g * hx[n * UNITS + o];
      X0out[(size_t)n * CSTRIDE + o]  = v;
      XS0out[(size_t)n * CSTRIDE + o] = dv * v;
    }
  } else {
#pragma unroll
    for (int j = 0; j < 8; ++j) {
      float g = 1.f / (1.f + expf(-acc[j]));
      UG[n * UNITS + (o0 - 64) + j] = g;
    }
  }
}

// ----------------------------------------------------- candidate + output ----
__global__ __launch_bounds__(256) void k_final(const float* __restrict__ X0,
                                               const float* __restrict__ X1,
                                               const float* __restrict__ X2,
                                               const float* __restrict__ w_c,
                                               const float* __restrict__ b_c,
                                               const float* __restrict__ hx,
                                               const float* __restrict__ UG,
                                               float* __restrict__ out) {
  __shared__ float xr[3][GN][66];
  const int n0 = blockIdx.x * GN;
  const int tid = threadIdx.x;
  for (int p = tid; p < GN * 66; p += 256) {
    int nl = p / 66, c = p % 66;
    size_t o = (size_t)(n0 + nl) * CSTRIDE + c;
    xr[0][nl][c] = X0[o];
    xr[1][nl][c] = X1[o];
    xr[2][nl][c] = X2[o];
  }
  __syncthreads();
  const int nl = tid >> 4;
  const int ot = tid & 15;
  const int o0 = ot * 4;
  float acc[4];
#pragma unroll
  for (int j = 0; j < 4; ++j) acc[j] = b_c[o0 + j];
  for (int c = 0; c < 66; ++c) {
    int f = (c < 64) ? (c + 2) : (c - 64);
#pragma unroll
    for (int m = 0; m < 3; ++m) {
      float xv = xr[m][nl][c];
      float4 w = *reinterpret_cast<const float4*>(&w_c[(size_t)(f * 3 + m) * 64 + o0]);
      acc[0] += xv * w.x; acc[1] += xv * w.y; acc[2] += xv * w.z; acc[3] += xv * w.w;
    }
  }
  const int n = n0 + nl;
#pragma unroll
  for (int j = 0; j < 4; ++j) {
    int o = o0 + j;
    float cc = tanhf(acc[j]);
    float u  = UG[n * UNITS + o];
    float h  = hx[n * UNITS + o];
    out[n * UNITS + o] = u * h + (1.f - u) * cc;
  }
}

// -------------------------------------------------------------- launcher ----
extern "C" void kernel_launch(void* const* d_in, const int* in_sizes, int n_in,
                              void* d_out, int out_size, void* d_ws, size_t ws_size,
                              hipStream_t stream) {
  const float* inp  = (const float*)d_in[0];   // [1, N*2]
  const float* hx   = (const float*)d_in[1];   // [1, N*64]
  const float* adj  = (const float*)d_in[2];   // [N, N]
  const float* w_ru = (const float*)d_in[3];   // [198, 128]
  const float* b_ru = (const float*)d_in[4];   // [128]
  const float* w_c  = (const float*)d_in[5];   // [198, 64]
  const float* b_c  = (const float*)d_in[6];   // [64]
  float* out = (float*)d_out;

  float* ws   = (float*)d_ws;
  float* dinv = ws;                         // 8192 (padded to 16384)
  float* X0   = ws + 16384;                 // [N][72]
  float* XS0  = X0 + NS;
  float* X1   = XS0 + NS;
  float* XS1  = X1 + NS;
  float* X2   = XS1 + NS;
  float* P    = X2 + NS;                    // SPLITS * [N][72]
  float* UG   = P + (size_t)SPLITS * NS;    // [N][64]

  dim3 gg(NN / BN, SPLITS);
  const int eb = NN * 66 / 256;             // 2112
  const int bb = NN * CSTRIDE / 256;        // 2304

  k_dinv <<<NN, 256, 0, stream>>>(adj, dinv);
  k_build<<<bb, 256, 0, stream>>>(hx, inp, dinv, X0, XS0);

  // gconv 1 (gates)
  k_gemm <<<gg, 256, 0, stream>>>(adj, XS0, P);
  k_epiA <<<eb, 256, 0, stream>>>(P, XS0, dinv, X1, XS1);
  k_gemm <<<gg, 256, 0, stream>>>(adj, XS1, P);
  k_epiB <<<eb, 256, 0, stream>>>(P, XS1, X0, X2);
  k_gates<<<NN / GN, 256, 0, stream>>>(X0, X1, X2, w_ru, b_ru, hx, dinv, X0, XS0, UG);

  // gconv 2 (candidate) — state cols now r*h, input cols reused
  k_gemm <<<gg, 256, 0, stream>>>(adj, XS0, P);
  k_epiA <<<eb, 256, 0, stream>>>(P, XS0, dinv, X1, XS1);
  k_gemm <<<gg, 256, 0, stream>>>(adj, XS1, P);
  k_epiB <<<eb, 256, 0, stream>>>(P, XS1, X0, X2);
  k_final<<<NN / GN, 256, 0, stream>>>(X0, X1, X2, w_c, b_c, hx, UG, out);
}

// Round 2
// 323.948 us; speedup vs baseline: 4.0697x; 4.0697x over previous
//
#include <hip/hip_runtime.h>
#include <math.h>

// DCGRU cell, N=8192, B=1, D_IN=2, UNITS=64, K=2 -> F=66, M=3.
// adj_mx @ v == adj^T @ (dinv*v) + (dinv*v)   (adj2 = adj + I folded in)
// Heavy GEMMs run on bf16 MFMA (v_mfma_f32_16x16x32_bf16), f32 accum.
// adjF: bf16 adj^T in fragment order: frag(mt,kb) = 1KB, element (lane l, j)
//   = adj[kb*32 + 8*(l>>4) + j][mt*16 + (l&15)]
// UtF:  bf16 U^T in fragment order: frag(kb,nt), element (l,j)
//   = U[kb*32 + 8*(l>>4) + j][nt*16 + (l&15)]   (cols padded 66..79 = 0)
// ws requirement: ~172 MB.

typedef __attribute__((ext_vector_type(8))) short short8v;
typedef __attribute__((ext_vector_type(4))) float f32x4;

constexpr int NN   = 8192;
constexpr int CST  = 80;                   // padded f32 row stride
constexpr int KBT  = 256;                  // k-blocks of 32
constexpr int SPLITS = 8;
constexpr int KB_PER = KBT / SPLITS;       // 32
constexpr size_t NS = (size_t)NN * CST;    // 655360 floats per matrix

static __device__ __forceinline__ ushort f2bf(float x) {
  union { float f; unsigned u; } c; c.f = x;
  unsigned u = c.u;
  u += 0x7fffu + ((u >> 16) & 1u);         // RNE
  return (ushort)(u >> 16);
}

static __device__ __forceinline__ void mfma_b16(f32x4& acc, short8v a, short8v b) {
  asm("v_mfma_f32_16x16x32_bf16 %0, %1, %2, %0" : "+v"(acc) : "v"(a), "v"(b));
}

// ---------------- adj -> bf16 fragment-order transpose + row-sum partials ----
__global__ __launch_bounds__(256) void k_conv(const float* __restrict__ adj,
                                              ushort* __restrict__ adjF,
                                              float* __restrict__ dpart) {
  __shared__ float tile[32][132];
  const int kb = blockIdx.x;               // 0..255 : k rows kb*32..+31
  const int half = blockIdx.y;             // 0..1   : i columns half*4096..
  const int tid = threadIdx.x;
  const int kr = tid >> 3;                 // 0..31 row in band
  const int c16 = (tid & 7) * 16;          // col offset in 128-chunk
  const int f = tid >> 6, l = tid & 63;
  const float* src = adj + ((size_t)kb * 32 + kr) * NN + half * 4096;
  float rs = 0.f;
  for (int ch = 0; ch < 32; ++ch) {
    float4 v0 = *(const float4*)(src + ch * 128 + c16);
    float4 v1 = *(const float4*)(src + ch * 128 + c16 + 4);
    float4 v2 = *(const float4*)(src + ch * 128 + c16 + 8);
    float4 v3 = *(const float4*)(src + ch * 128 + c16 + 12);
    rs += (v0.x + v0.y + v0.z + v0.w) + (v1.x + v1.y + v1.z + v1.w)
        + (v2.x + v2.y + v2.z + v2.w) + (v3.x + v3.y + v3.z + v3.w);
    *(float4*)&tile[kr][c16]      = v0;
    *(float4*)&tile[kr][c16 + 4]  = v1;
    *(float4*)&tile[kr][c16 + 8]  = v2;
    *(float4*)&tile[kr][c16 + 12] = v3;
    __syncthreads();
#pragma unroll
    for (int h = 0; h < 2; ++h) {
      int fl = f + h * 4;                  // 0..7 fragment within chunk
      int mt = half * 256 + ch * 8 + fl;
      short8v o;
#pragma unroll
      for (int j = 0; j < 8; ++j)
        o[j] = (short)f2bf(tile[8 * (l >> 4) + j][fl * 16 + (l & 15)]);
      *(short8v*)(adjF + ((size_t)mt * KBT + kb) * 512 + l * 8) = o;
    }
    __syncthreads();
  }
  rs += __shfl_down(rs, 4);
  rs += __shfl_down(rs, 2);
  rs += __shfl_down(rs, 1);
  if ((tid & 7) == 0) dpart[half * NN + kb * 32 + kr] = rs;
}

__global__ __launch_bounds__(256) void k_dfix(const float* __restrict__ dpart,
                                              float* __restrict__ dinv) {
  int i = blockIdx.x * 256 + threadIdx.x;
  dinv[i] = 1.f / (dpart[i] + dpart[NN + i] + 1.f);
}

// ---------------- build X0 (f32 [N][80]) , XS0 , UtF(XS0) --------------------
__global__ __launch_bounds__(256) void k_build(const float* __restrict__ hx,
                                               const float* __restrict__ inp,
                                               const float* __restrict__ dinv,
                                               float* __restrict__ X0,
                                               float* __restrict__ XS0,
                                               ushort* __restrict__ UtF) {
  const int n0 = blockIdx.x * 32;
  const int tid = threadIdx.x;
  for (int p = tid; p < 32 * 20; p += 256) {
    int nl = p / 20, c4 = (p % 20) * 4;
    int n = n0 + nl;
    float dv = dinv[n];
    float v[4];
#pragma unroll
    for (int j = 0; j < 4; ++j) {
      int c = c4 + j;
      v[j] = (c < 64) ? hx[n * 64 + c] : (c < 66 ? inp[n * 2 + (c - 64)] : 0.f);
    }
    size_t o = (size_t)n * CST + c4;
    *(float4*)(X0 + o)  = make_float4(v[0], v[1], v[2], v[3]);
    *(float4*)(XS0 + o) = make_float4(dv * v[0], dv * v[1], dv * v[2], dv * v[3]);
  }
  for (int p = tid; p < 5 * 64; p += 256) {
    int nt = p >> 6, l = p & 63;
    short8v o8;
#pragma unroll
    for (int j = 0; j < 8; ++j) {
      int n = n0 + 8 * (l >> 4) + j;
      int c = nt * 16 + (l & 15);
      float v = (c < 64) ? hx[n * 64 + c] : (c < 66 ? inp[n * 2 + (c - 64)] : 0.f);
      o8[j] = (short)f2bf(v * dinv[n]);
    }
    *(short8v*)(UtF + ((size_t)blockIdx.x * 5 + nt) * 512 + l * 8) = o8;
  }
}

// ---------------- MFMA GEMM: P[split] = adj^T-chunk @ U ----------------------
__global__ __launch_bounds__(256) void k_gemm(const ushort* __restrict__ adjF,
                                              const ushort* __restrict__ UtF,
                                              float* __restrict__ P) {
  const int w = threadIdx.x >> 6, l = threadIdx.x & 63;
  const int mt = blockIdx.x * 4 + w;             // 0..511
  const int kb0 = blockIdx.y * KB_PER;
  f32x4 acc[5];
#pragma unroll
  for (int nt = 0; nt < 5; ++nt) acc[nt] = (f32x4){0.f, 0.f, 0.f, 0.f};
  const ushort* ap = adjF + ((size_t)mt * KBT + kb0) * 512 + l * 8;
  const ushort* bp = UtF + (size_t)kb0 * 5 * 512 + l * 8;
#pragma unroll 4
  for (int kb = 0; kb < KB_PER; ++kb) {
    short8v a = *(const short8v*)(ap + kb * 512);
#pragma unroll
    for (int nt = 0; nt < 5; ++nt) {
      short8v b = *(const short8v*)(bp + (size_t)(kb * 5 + nt) * 512);
      mfma_b16(acc[nt], a, b);
    }
  }
  asm volatile("s_nop 7\n\ts_nop 7\n\ts_nop 7" ::: "memory");  // MFMA->read hazard guard
  // D row = (l>>4)*4 + r, col = l&15  (HW-verified C/D layout)
  float* Pp = P + (size_t)blockIdx.y * NS + ((size_t)mt * 16 + (l >> 4) * 4) * CST + (l & 15);
#pragma unroll
  for (int nt = 0; nt < 5; ++nt)
#pragma unroll
    for (int r = 0; r < 4; ++r)
      Pp[(size_t)r * CST + nt * 16] = acc[nt][r];
}

// ---------------- epilogue A: X1 = sumP + XSin ; XS1 = dinv*X1 ; UtF(XS1) ----
__global__ __launch_bounds__(256) void k_epiA(const float* __restrict__ P,
                                              const float* __restrict__ XSin,
                                              const float* __restrict__ dinv,
                                              float* __restrict__ X1,
                                              float* __restrict__ XS1,
                                              ushort* __restrict__ UtF) {
  __shared__ float xs[32][84];
  const int n0 = blockIdx.x * 32;
  const int tid = threadIdx.x;
  for (int p = tid; p < 32 * 20; p += 256) {
    int nl = p / 20, c4 = (p % 20) * 4;
    int n = n0 + nl;
    size_t o = (size_t)n * CST + c4;
    float4 s = *(const float4*)(XSin + o);
#pragma unroll
    for (int sp = 0; sp < SPLITS; ++sp) {
      float4 t = *(const float4*)(P + (size_t)sp * NS + o);
      s.x += t.x; s.y += t.y; s.z += t.z; s.w += t.w;
    }
    *(float4*)(X1 + o) = s;
    float dv = dinv[n];
    float4 z = make_float4(dv * s.x, dv * s.y, dv * s.z, dv * s.w);
    *(float4*)(XS1 + o) = z;
    *(float4*)&xs[nl][c4] = z;
  }
  __syncthreads();
  for (int p = tid; p < 5 * 64; p += 256) {
    int nt = p >> 6, l = p & 63;
    short8v o8;
#pragma unroll
    for (int j = 0; j < 8; ++j)
      o8[j] = (short)f2bf(xs[8 * (l >> 4) + j][nt * 16 + (l & 15)]);
    *(short8v*)(UtF + ((size_t)blockIdx.x * 5 + nt) * 512 + l * 8) = o8;
  }
}

// ---------------- epilogue B: X2 = 2*(sumP + XSin) - X0 ----------------------
__global__ __launch_bounds__(256) void k_epiB(const float* __restrict__ P,
                                              const float* __restrict__ XSin,
                                              const float* __restrict__ X0,
                                              float* __restrict__ X2) {
  const int n0 = blockIdx.x * 32;
  const int tid = threadIdx.x;
  for (int p = tid; p < 32 * 20; p += 256) {
    int nl = p / 20, c4 = (p % 20) * 4;
    size_t o = (size_t)(n0 + nl) * CST + c4;
    float4 s = *(const float4*)(XSin + o);
#pragma unroll
    for (int sp = 0; sp < SPLITS; ++sp) {
      float4 t = *(const float4*)(P + (size_t)sp * NS + o);
      s.x += t.x; s.y += t.y; s.z += t.z; s.w += t.w;
    }
    float4 x0 = *(const float4*)(X0 + o);
    *(float4*)(X2 + o) = make_float4(2.f * s.x - x0.x, 2.f * s.y - x0.y,
                                     2.f * s.z - x0.z, 2.f * s.w - x0.w);
  }
}

// ---------------- gates: sigmoid matmul; update X0/XS0 (r*h), UtF, UG --------
__global__ __launch_bounds__(256) void k_gates(const float* __restrict__ X0,
    const float* __restrict__ X1, const float* __restrict__ X2,
    const float* __restrict__ w_ru, const float* __restrict__ b_ru,
    const float* __restrict__ hx, const float* __restrict__ inp,
    const float* __restrict__ dinv,
    float* __restrict__ X0w, float* __restrict__ XS0w,
    ushort* __restrict__ UtF, float* __restrict__ UG) {
  __shared__ float xr[3][32][68];
  __shared__ float rhq[32][64];
  const int n0 = blockIdx.x * 32;
  const int tid = threadIdx.x;
  for (int p = tid; p < 32 * 17; p += 256) {
    int nl = p / 17, c4 = (p % 17) * 4;
    size_t o = (size_t)(n0 + nl) * CST + c4;
    *(float4*)&xr[0][nl][c4] = *(const float4*)(X0 + o);
    *(float4*)&xr[1][nl][c4] = *(const float4*)(X1 + o);
    *(float4*)&xr[2][nl][c4] = *(const float4*)(X2 + o);
  }
  __syncthreads();
  const int nl = tid >> 3, og = tid & 7, o0 = og * 16;
  float acc[16];
#pragma unroll
  for (int j = 0; j < 16; ++j) acc[j] = b_ru[o0 + j];
  for (int c = 0; c < 66; ++c) {
    int f = (c < 64) ? (c + 2) : (c - 64);
    const float* wr = w_ru + (size_t)(f * 3) * 128 + o0;
#pragma unroll
    for (int m = 0; m < 3; ++m) {
      float xv = xr[m][nl][c];
      float wl[16];
      *(float4*)(wl)      = *(const float4*)(wr + m * 128);
      *(float4*)(wl + 4)  = *(const float4*)(wr + m * 128 + 4);
      *(float4*)(wl + 8)  = *(const float4*)(wr + m * 128 + 8);
      *(float4*)(wl + 12) = *(const float4*)(wr + m * 128 + 12);
#pragma unroll
      for (int j = 0; j < 16; ++j) acc[j] += xv * wl[j];
    }
  }
  const int n = n0 + nl;
  const float dv = dinv[n];
  if (og < 4) {
#pragma unroll
    for (int j = 0; j < 16; ++j) {
      int o = o0 + j;
      float r = 1.f / (1.f + expf(-acc[j]));
      float rh = r * hx[n * 64 + o];
      X0w[(size_t)n * CST + o] = rh;
      float srh = dv * rh;
      XS0w[(size_t)n * CST + o] = srh;
      rhq[nl][o] = srh;
    }
  } else {
#pragma unroll
    for (int j = 0; j < 16; ++j)
      UG[n * 64 + (o0 - 64) + j] = 1.f / (1.f + expf(-acc[j]));
  }
  __syncthreads();
  for (int p = tid; p < 5 * 64; p += 256) {
    int nt = p >> 6, l = p & 63;
    short8v o8;
#pragma unroll
    for (int j = 0; j < 8; ++j) {
      int nloc = 8 * (l >> 4) + j;
      int nn = n0 + nloc;
      int c = nt * 16 + (l & 15);
      float v;
      if (c < 64)      v = rhq[nloc][c];
      else if (c < 66) v = dinv[nn] * inp[nn * 2 + (c - 64)];
      else             v = 0.f;
      o8[j] = (short)f2bf(v);
    }
    *(short8v*)(UtF + ((size_t)blockIdx.x * 5 + nt) * 512 + l * 8) = o8;
  }
}

// ---------------- candidate + output -----------------------------------------
__global__ __launch_bounds__(256) void k_final(const float* __restrict__ X0,
    const float* __restrict__ X1, const float* __restrict__ X2,
    const float* __restrict__ w_c, const float* __restrict__ b_c,
    const float* __restrict__ hx, const float* __restrict__ UG,
    float* __restrict__ out) {
  __shared__ float xr[3][16][68];
  const int n0 = blockIdx.x * 16;
  const int tid = threadIdx.x;
  for (int p = tid; p < 16 * 17; p += 256) {
    int nl = p / 17, c4 = (p % 17) * 4;
    size_t o = (size_t)(n0 + nl) * CST + c4;
    *(float4*)&xr[0][nl][c4] = *(const float4*)(X0 + o);
    *(float4*)&xr[1][nl][c4] = *(const float4*)(X1 + o);
    *(float4*)&xr[2][nl][c4] = *(const float4*)(X2 + o);
  }
  __syncthreads();
  const int nl = tid >> 4, ot = tid & 15, o0 = ot * 4;
  float acc[4];
#pragma unroll
  for (int j = 0; j < 4; ++j) acc[j] = b_c[o0 + j];
  for (int c = 0; c < 66; ++c) {
    int f = (c < 64) ? (c + 2) : (c - 64);
#pragma unroll
    for (int m = 0; m < 3; ++m) {
      float xv = xr[m][nl][c];
      float wl[4];
      *(float4*)(wl) = *(const float4*)(w_c + (size_t)(f * 3 + m) * 64 + o0);
#pragma unroll
      for (int j = 0; j < 4; ++j) acc[j] += xv * wl[j];
    }
  }
  const int n = n0 + nl;
#pragma unroll
  for (int j = 0; j < 4; ++j) {
    int o = o0 + j;
    float cc = tanhf(acc[j]);
    float u = UG[n * 64 + o];
    float h = hx[n * 64 + o];
    out[n * 64 + o] = u * h + (1.f - u) * cc;
  }
}

// ---------------- launcher ----------------------------------------------------
extern "C" void kernel_launch(void* const* d_in, const int* in_sizes, int n_in,
                              void* d_out, int out_size, void* d_ws, size_t ws_size,
                              hipStream_t stream) {
  const float* inp  = (const float*)d_in[0];
  const float* hx   = (const float*)d_in[1];
  const float* adj  = (const float*)d_in[2];
  const float* w_ru = (const float*)d_in[3];
  const float* b_ru = (const float*)d_in[4];
  const float* w_c  = (const float*)d_in[5];
  const float* b_c  = (const float*)d_in[6];
  float* out = (float*)d_out;

  float* ws    = (float*)d_ws;
  float* dinv  = ws;                       // 8192
  float* dpart = ws + 8192;                // 2*8192
  float* X0    = ws + 24576;               // [N][80] each
  float* XS0   = X0 + NS;
  float* X1    = XS0 + NS;
  float* XS1   = X1 + NS;
  float* X2    = XS1 + NS;
  float* P     = X2 + NS;                  // SPLITS * NS
  float* UG    = P + (size_t)SPLITS * NS;  // [N][64]
  ushort* UtF  = (ushort*)(UG + (size_t)NN * 64);          // 1.25 MB
  ushort* adjF = UtF + (size_t)KBT * 5 * 512;              // 128 MB

  dim3 cg(KBT, 2);
  dim3 gg(NN / 64, SPLITS);

  k_conv <<<cg, 256, 0, stream>>>(adj, adjF, dpart);
  k_dfix <<<NN / 256, 256, 0, stream>>>(dpart, dinv);
  k_build<<<NN / 32, 256, 0, stream>>>(hx, inp, dinv, X0, XS0, UtF);

  // gconv 1 (gates)
  k_gemm <<<gg, 256, 0, stream>>>(adjF, UtF, P);
  k_epiA <<<NN / 32, 256, 0, stream>>>(P, XS0, dinv, X1, XS1, UtF);
  k_gemm <<<gg, 256, 0, stream>>>(adjF, UtF, P);
  k_epiB <<<NN / 32, 256, 0, stream>>>(P, XS1, X0, X2);
  k_gates<<<NN / 32, 256, 0, stream>>>(X0, X1, X2, w_ru, b_ru, hx, inp, dinv,
                                       X0, XS0, UtF, UG);

  // gconv 2 (candidate)
  k_gemm <<<gg, 256, 0, stream>>>(adjF, UtF, P);
  k_epiA <<<NN / 32, 256, 0, stream>>>(P, XS0, dinv, X1, XS1, UtF);
  k_gemm <<<gg, 256, 0, stream>>>(adjF, UtF, P);
  k_epiB <<<NN / 32, 256, 0, stream>>>(P, XS1, X0, X2);
  k_final<<<NN / 16, 256, 0, stream>>>(X0, X1, X2, w_c, b_c, hx, UG, out);
}